// Round 1
// baseline (449.763 us; speedup 1.0000x reference)
//
#include <hip/hip_runtime.h>
#include <hip/hip_bf16.h>

// ---------------------------------------------------------------------------
// OutliersQLinearColumn: out = x @ w^T + bias
//   w = sign(weight - row_mean) * row_mean_abs, with fp32 outlier columns
//       scattered in (last-occurrence-wins on duplicate indices).
// Strategy: quantize weight -> bf16 [OC,IC], cast x -> bf16 [M,IC],
//           bf16 MFMA GEMM (m97-style 128x128 tile, global_load_lds w=16).
// ---------------------------------------------------------------------------

typedef __attribute__((ext_vector_type(8))) __bf16 bf16x8;
typedef __attribute__((ext_vector_type(4))) float  f32x4;
typedef unsigned short us4 __attribute__((ext_vector_type(4)));
typedef unsigned short us8 __attribute__((ext_vector_type(8)));

__device__ inline unsigned short f2bf(float f) {
    unsigned u = __float_as_uint(f);
    unsigned r = (u + 0x7FFFu + ((u >> 16) & 1u)) >> 16;  // RNE
    return (unsigned short)r;
}

// ---------------------------------------------------------------------------
// col_map: for each input column, the outlier slot j that lands there
// (largest j wins == NumPy fancy-assignment last-wins), or -1.
// ---------------------------------------------------------------------------
__global__ void init_colmap_kernel(int* __restrict__ cm, int IC) {
    int i = blockIdx.x * 256 + threadIdx.x;
    if (i < IC) cm[i] = -1;
}

__global__ void scatter_colmap_kernel(const int* __restrict__ idx,
                                      int* __restrict__ cm, int n) {
    int j = blockIdx.x * 256 + threadIdx.x;
    if (j < n) atomicMax(&cm[idx[j]], j);
}

// ---------------------------------------------------------------------------
// Quantize one weight row per block (256 threads, IC == 4096).
// ---------------------------------------------------------------------------
__global__ void quant_weight_kernel(const float* __restrict__ w,
                                    const float* __restrict__ ow,
                                    const int* __restrict__ cm,
                                    unsigned short* __restrict__ wq,
                                    int IC, int n_out) {
    __shared__ float red[8];
    const int o = blockIdx.x;
    const int t = threadIdx.x;
    const int lane = t & 63, wid = t >> 6;

    const float4* row4 = (const float4*)(w + (size_t)o * IC);
    float4 v[4];
    float s = 0.f;
#pragma unroll
    for (int j = 0; j < 4; ++j) {
        v[j] = row4[t + j * 256];
        s += v[j].x + v[j].y + v[j].z + v[j].w;
    }
#pragma unroll
    for (int off = 32; off; off >>= 1) s += __shfl_down(s, off);
    if (lane == 0) red[wid] = s;
    __syncthreads();
    const float mean = (red[0] + red[1] + red[2] + red[3]) / (float)IC;

    float a = 0.f;
#pragma unroll
    for (int j = 0; j < 4; ++j)
        a += fabsf(v[j].x - mean) + fabsf(v[j].y - mean) +
             fabsf(v[j].z - mean) + fabsf(v[j].w - mean);
#pragma unroll
    for (int off = 32; off; off >>= 1) a += __shfl_down(a, off);
    if (lane == 0) red[4 + wid] = a;
    __syncthreads();
    const float scale = (red[4] + red[5] + red[6] + red[7]) / (float)IC;

    const size_t base = (size_t)o * IC;
    const float* owr = ow + (size_t)o * n_out;
#pragma unroll
    for (int j = 0; j < 4; ++j) {
        const int c0 = (t + j * 256) * 4;
        float e0 = v[j].x, e1 = v[j].y, e2 = v[j].z, e3 = v[j].w;
        float ee[4] = {e0, e1, e2, e3};
        us4 q4;
#pragma unroll
        for (int ei = 0; ei < 4; ++ei) {
            float c = ee[ei] - mean;
            float q = c > 0.f ? scale : (c < 0.f ? -scale : 0.f);
            int m = cm[c0 + ei];
            if (m >= 0) q = owr[m];
            q4[ei] = f2bf(q);
        }
        *(us4*)&wq[base + c0] = q4;
    }
}

// ---------------------------------------------------------------------------
// Cast x f32 -> bf16, 8 elements/thread/iter, grid-stride.
// ---------------------------------------------------------------------------
__global__ void cast_x_kernel(const float4* __restrict__ x4,
                              us8* __restrict__ xb, long n8) {
    long i = (long)blockIdx.x * blockDim.x + threadIdx.x;
    const long stride = (long)gridDim.x * blockDim.x;
    for (; i < n8; i += stride) {
        float4 a = x4[i * 2], b = x4[i * 2 + 1];
        us8 o;
        o[0] = f2bf(a.x); o[1] = f2bf(a.y); o[2] = f2bf(a.z); o[3] = f2bf(a.w);
        o[4] = f2bf(b.x); o[5] = f2bf(b.y); o[6] = f2bf(b.z); o[7] = f2bf(b.w);
        xb[i] = o;
    }
}

// ---------------------------------------------------------------------------
// GEMM: C[M,N] = A[M,K](bf16) * B[N,K](bf16)^T + bias, C fp32.
// 128x128 tile, BK=64, 256 threads (4 waves), each wave a 64x64 quadrant
// (4x4 fragments of 16x16x32 MFMA). global_load_lds width-16 staging.
// ---------------------------------------------------------------------------
#define BM 128
#define BN 128
#define BK 64

__global__ __launch_bounds__(256) void gemm_bt_kernel(
    const unsigned short* __restrict__ A,   // [M,K] bf16 bits
    const unsigned short* __restrict__ B,   // [N,K] bf16 bits
    const float* __restrict__ bias,         // [N]
    float* __restrict__ C,                  // [M,N] f32
    int M, int N, int K) {
    __shared__ unsigned short sA[BM * BK];
    __shared__ unsigned short sB[BN * BK];

    const int t = threadIdx.x;
    const int wid = t >> 6, lane = t & 63;
    const int tm = blockIdx.y * BM, tn = blockIdx.x * BN;
    const int wr = wid >> 1, wc = wid & 1;

    f32x4 acc[4][4] = {};

    const unsigned short* Abase = A + (size_t)tm * K;
    const unsigned short* Bbase = B + (size_t)tn * K;

    // bias values for this wave's 4 column fragments
    float bv[4];
#pragma unroll
    for (int ni = 0; ni < 4; ++ni)
        bv[ni] = bias[tn + wc * 64 + ni * 16 + (lane & 15)];

    const int srow = (lane >> 3);          // row within 8-row chunk
    const int scol = (lane & 7) * 8;       // bf16 column offset (16B granules)

    for (int k0 = 0; k0 < K; k0 += BK) {
        __syncthreads();
#pragma unroll
        for (int i = 0; i < 4; ++i) {
            const int c = i * 4 + wid;           // chunk 0..15 -> rows c*8..c*8+7
            const int row = c * 8 + srow;
            __builtin_amdgcn_global_load_lds(
                (const __attribute__((address_space(1))) void*)(Abase + (size_t)row * K + k0 + scol),
                (__attribute__((address_space(3))) void*)(&sA[c * 8 * BK]),
                16, 0, 0);
            __builtin_amdgcn_global_load_lds(
                (const __attribute__((address_space(1))) void*)(Bbase + (size_t)row * K + k0 + scol),
                (__attribute__((address_space(3))) void*)(&sB[c * 8 * BK]),
                16, 0, 0);
        }
        __syncthreads();

#pragma unroll
        for (int kk = 0; kk < BK; kk += 32) {
            const int krd = kk + (lane >> 4) * 8;
            bf16x8 af[4], bfr[4];
#pragma unroll
            for (int mi = 0; mi < 4; ++mi) {
                const int r = wr * 64 + mi * 16 + (lane & 15);
                af[mi] = *reinterpret_cast<const bf16x8*>(&sA[r * BK + krd]);
            }
#pragma unroll
            for (int ni = 0; ni < 4; ++ni) {
                const int r = wc * 64 + ni * 16 + (lane & 15);
                bfr[ni] = *reinterpret_cast<const bf16x8*>(&sB[r * BK + krd]);
            }
#pragma unroll
            for (int mi = 0; mi < 4; ++mi)
#pragma unroll
                for (int ni = 0; ni < 4; ++ni)
                    acc[mi][ni] = __builtin_amdgcn_mfma_f32_16x16x32_bf16(
                        af[mi], bfr[ni], acc[mi][ni], 0, 0, 0);
        }
    }

    // Epilogue: C/D layout col = lane&15, row = (lane>>4)*4 + reg
    const int crow = tm + wr * 64;
    const int ccol = tn + wc * 64 + (lane & 15);
#pragma unroll
    for (int mi = 0; mi < 4; ++mi) {
#pragma unroll
        for (int r = 0; r < 4; ++r) {
            const int row = crow + mi * 16 + (lane >> 4) * 4 + r;
            float* Crow = C + (size_t)row * N;
#pragma unroll
            for (int ni = 0; ni < 4; ++ni)
                Crow[ccol + ni * 16] = acc[mi][ni][r] + bv[ni];
        }
    }
}

// ---------------------------------------------------------------------------
extern "C" void kernel_launch(void* const* d_in, const int* in_sizes, int n_in,
                              void* d_out, int out_size, void* d_ws, size_t ws_size,
                              hipStream_t stream) {
    const float* x      = (const float*)d_in[0];
    const float* weight = (const float*)d_in[1];
    const float* bias   = (const float*)d_in[2];
    const float* ow     = (const float*)d_in[3];
    const int*   idx    = (const int*)d_in[4];

    const int OC    = in_sizes[2];
    const int n_out = in_sizes[4];
    const int IC    = in_sizes[1] / OC;
    const int M     = in_sizes[0] / IC;
    float* out = (float*)d_out;

    char* ws = (char*)d_ws;
    unsigned short* wq = (unsigned short*)ws;                              // OC*IC bf16
    unsigned short* xb = (unsigned short*)(ws + (size_t)OC * IC * 2);      // M*IC bf16
    int* cm = (int*)(ws + (size_t)OC * IC * 2 + (size_t)M * IC * 2);       // IC ints

    init_colmap_kernel<<<(IC + 255) / 256, 256, 0, stream>>>(cm, IC);
    scatter_colmap_kernel<<<(n_out + 255) / 256, 256, 0, stream>>>(idx, cm, n_out);
    quant_weight_kernel<<<OC, 256, 0, stream>>>(weight, ow, cm, wq, IC, n_out);

    const long n8 = (long)M * IC / 8;
    cast_x_kernel<<<2048, 256, 0, stream>>>((const float4*)x, (us8*)xb, n8);

    dim3 grid(OC / BN, M / BM);
    gemm_bt_kernel<<<grid, 256, 0, stream>>>(xb, wq, bias, out, M, OC, IC);
}

// Round 2
// 310.881 us; speedup vs baseline: 1.4467x; 1.4467x over previous
//
#include <hip/hip_runtime.h>
#include <hip/hip_bf16.h>

// ---------------------------------------------------------------------------
// OutliersQLinearColumn: out = x @ w^T + bias
// Round 2: 8-phase 256x256 deep-pipelined bf16 MFMA GEMM (T3+T4+T5+T1).
//   - k-split LDS sub-tiles [256][32] (64-B rows) -> ds_read_b128 at LDS
//     bank floor, no swizzle needed, global_load_lds stays linear.
//   - counted vmcnt(4) (never 0 in main loop), raw s_barrier, setprio(1)
//     around each 16-MFMA cluster, bijective XCD blockIdx swizzle.
// ---------------------------------------------------------------------------

typedef __attribute__((ext_vector_type(8))) __bf16 bf16x8;
typedef __attribute__((ext_vector_type(4))) float  f32x4;
typedef unsigned short us4 __attribute__((ext_vector_type(4)));
typedef unsigned short us8 __attribute__((ext_vector_type(8)));

__device__ inline unsigned short f2bf(float f) {
    unsigned u = __float_as_uint(f);
    unsigned r = (u + 0x7FFFu + ((u >> 16) & 1u)) >> 16;  // RNE
    return (unsigned short)r;
}

// ---------------------------------------------------------------------------
// col_map: for each input column, outlier slot j landing there (last wins).
// ---------------------------------------------------------------------------
__global__ void init_colmap_kernel(int* __restrict__ cm, int IC) {
    int i = blockIdx.x * 256 + threadIdx.x;
    if (i < IC) cm[i] = -1;
}

__global__ void scatter_colmap_kernel(const int* __restrict__ idx,
                                      int* __restrict__ cm, int n) {
    int j = blockIdx.x * 256 + threadIdx.x;
    if (j < n) atomicMax(&cm[idx[j]], j);
}

// ---------------------------------------------------------------------------
// Quantize one weight row per block (256 threads, IC == 4096).
// ---------------------------------------------------------------------------
__global__ void quant_weight_kernel(const float* __restrict__ w,
                                    const float* __restrict__ ow,
                                    const int* __restrict__ cm,
                                    unsigned short* __restrict__ wq,
                                    int IC, int n_out) {
    __shared__ float red[8];
    const int o = blockIdx.x;
    const int t = threadIdx.x;
    const int lane = t & 63, wid = t >> 6;

    const float4* row4 = (const float4*)(w + (size_t)o * IC);
    float4 v[4];
    float s = 0.f;
#pragma unroll
    for (int j = 0; j < 4; ++j) {
        v[j] = row4[t + j * 256];
        s += v[j].x + v[j].y + v[j].z + v[j].w;
    }
#pragma unroll
    for (int off = 32; off; off >>= 1) s += __shfl_down(s, off);
    if (lane == 0) red[wid] = s;
    __syncthreads();
    const float mean = (red[0] + red[1] + red[2] + red[3]) / (float)IC;

    float a = 0.f;
#pragma unroll
    for (int j = 0; j < 4; ++j)
        a += fabsf(v[j].x - mean) + fabsf(v[j].y - mean) +
             fabsf(v[j].z - mean) + fabsf(v[j].w - mean);
#pragma unroll
    for (int off = 32; off; off >>= 1) a += __shfl_down(a, off);
    if (lane == 0) red[4 + wid] = a;
    __syncthreads();
    const float scale = (red[4] + red[5] + red[6] + red[7]) / (float)IC;

    const size_t base = (size_t)o * IC;
    const float* owr = ow + (size_t)o * n_out;
#pragma unroll
    for (int j = 0; j < 4; ++j) {
        const int c0 = (t + j * 256) * 4;
        float ee[4] = {v[j].x, v[j].y, v[j].z, v[j].w};
        us4 q4;
#pragma unroll
        for (int ei = 0; ei < 4; ++ei) {
            float c = ee[ei] - mean;
            float q = c > 0.f ? scale : (c < 0.f ? -scale : 0.f);
            int m = cm[c0 + ei];
            if (m >= 0) q = owr[m];
            q4[ei] = f2bf(q);
        }
        *(us4*)&wq[base + c0] = q4;
    }
}

// ---------------------------------------------------------------------------
// Cast x f32 -> bf16, 8 elements/thread/iter, grid-stride.
// ---------------------------------------------------------------------------
__global__ void cast_x_kernel(const float4* __restrict__ x4,
                              us8* __restrict__ xb, long n8) {
    long i = (long)blockIdx.x * blockDim.x + threadIdx.x;
    const long stride = (long)gridDim.x * blockDim.x;
    for (; i < n8; i += stride) {
        float4 a = x4[i * 2], b = x4[i * 2 + 1];
        us8 o;
        o[0] = f2bf(a.x); o[1] = f2bf(a.y); o[2] = f2bf(a.z); o[3] = f2bf(a.w);
        o[4] = f2bf(b.x); o[5] = f2bf(b.y); o[6] = f2bf(b.z); o[7] = f2bf(b.w);
        xb[i] = o;
    }
}

// ---------------------------------------------------------------------------
// 8-phase 256x256 GEMM: C[M,N] = A[M,K](bf16) * B[N,K](bf16)^T + bias.
// 512 threads = 8 waves (2 M x 4 N), per-wave output 128x64.
// LDS (dynamic 128 KiB): lds[buf2][mat2][kh2][256 rows][32 k] bf16.
//   per-buf stride 32768 us, mat stride 16384, kh stride 8192, row stride 32.
// Per K-tile (BK=64): 4 phases (fragHalf x kHalf), each phase:
//   {ds_read 8|4 x b128 ; stage one half-tile (2 x global_load_lds w=16) ;
//    [vmcnt(4) twice per tile] ; s_barrier ; lgkmcnt(0)+sched_barrier(0) ;
//    setprio(1) ; 16 MFMA ; setprio(0) ; s_barrier}
// ---------------------------------------------------------------------------
#define BK 64

#define GLDS(src, dst) __builtin_amdgcn_global_load_lds( \
    (const __attribute__((address_space(1))) void*)(src), \
    (__attribute__((address_space(3))) void*)(dst), 16, 0, 0)

// Stage half-tile (MAT: 0=A,1=B ; KHS: k-half) of the tile at k-offset kn
// into buffer bufS. 2 x global_load_lds per thread (512 thr x 16 B x 2 = 16 KB).
#define STAGE(MAT, KHS, bufS, kn) do {                                        \
    const unsigned short* gsrc_ = (MAT) ? Bblk : Ablk;                        \
    _Pragma("unroll")                                                         \
    for (int rr_ = 0; rr_ < 2; ++rr_) {                                       \
      GLDS(gsrc_ + (size_t)(rr_ * 128 + stg_row) * K + (kn) + (KHS) * 32 + stg_col, \
           &lds[(bufS) * 32768 + (MAT) * 16384 + (KHS) * 8192 +               \
                (rr_ * 128 + wid * 16) * 32]);                                \
    } } while (0)

#define PHASE(FH, KH, DOBF, STMAT, STKH, VM, bufR, bufS, kn) do {             \
    const unsigned short* pA_ = &lds[(bufR) * 32768 + (KH) * 8192];           \
    const unsigned short* pB_ = &lds[(bufR) * 32768 + 16384 + (KH) * 8192];   \
    _Pragma("unroll")                                                         \
    for (int j_ = 0; j_ < 4; ++j_)                                            \
      af[j_] = *(const bf16x8*)&pA_[(wr * 128 + ((FH) * 4 + j_) * 16 + l15) * 32 + c8]; \
    if (DOBF) {                                                               \
      _Pragma("unroll")                                                       \
      for (int j_ = 0; j_ < 4; ++j_)                                          \
        bfr[j_] = *(const bf16x8*)&pB_[(wc * 64 + j_ * 16 + l15) * 32 + c8];  \
    }                                                                         \
    STAGE(STMAT, STKH, bufS, kn);                                             \
    if (VM) asm volatile("s_waitcnt vmcnt(4)" ::: "memory");                  \
    __builtin_amdgcn_s_barrier();                                             \
    asm volatile("s_waitcnt lgkmcnt(0)" ::: "memory");                        \
    __builtin_amdgcn_sched_barrier(0);                                        \
    __builtin_amdgcn_s_setprio(1);                                            \
    _Pragma("unroll")                                                         \
    for (int mi_ = 0; mi_ < 4; ++mi_)                                         \
      _Pragma("unroll")                                                       \
      for (int ni_ = 0; ni_ < 4; ++ni_)                                       \
        acc[(FH) * 4 + mi_][ni_] = __builtin_amdgcn_mfma_f32_16x16x32_bf16(   \
            af[mi_], bfr[ni_], acc[(FH) * 4 + mi_][ni_], 0, 0, 0);            \
    __builtin_amdgcn_s_setprio(0);                                            \
    __builtin_amdgcn_s_barrier();                                             \
  } while (0)

// One K-tile = 4 phases. Stages the NEXT tile (k-offset kn) into bufS.
// vmcnt(4) at end of P1 (covers this tile's kh1) and P3 (covers next kh0).
#define KTILE(bufR, bufS, kn) do {                                            \
    PHASE(0, 0, true,  0, 0, false, bufR, bufS, kn);                          \
    PHASE(1, 0, false, 1, 0, true,  bufR, bufS, kn);                          \
    PHASE(0, 1, true,  0, 1, false, bufR, bufS, kn);                          \
    PHASE(1, 1, false, 1, 1, true,  bufR, bufS, kn);                          \
  } while (0)

__global__ __launch_bounds__(512, 2) void gemm_8phase_kernel(
    const unsigned short* __restrict__ A,   // [M,K] bf16 bits
    const unsigned short* __restrict__ B,   // [N,K] bf16 bits
    const float* __restrict__ bias,         // [N]
    float* __restrict__ C,                  // [M,N] f32
    int M, int N, int K, int NBN) {
    extern __shared__ unsigned short lds[];  // 131072 B

    const int t = threadIdx.x;
    const int wid = t >> 6, lane = t & 63;
    const int l15 = lane & 15;
    const int c8 = (lane >> 4) * 8;          // k-chunk offset within 32-k half
    const int wr = wid >> 2;                 // 0..1  (M half)
    const int wc = wid & 3;                  // 0..3  (N quarter)
    const int stg_row = wid * 16 + (lane >> 2);
    const int stg_col = (lane & 3) * 8;

    // bijective XCD swizzle (m204)
    const int nwg = gridDim.x;
    const int bid = blockIdx.x;
    const int q = nwg >> 3, r = nwg & 7;
    const int xcd = bid & 7, off = bid >> 3;
    const int swz = (xcd < r ? xcd * (q + 1) : r * (q + 1) + (xcd - r) * q) + off;
    const int bm = swz / NBN, bn = swz % NBN;

    const unsigned short* Ablk = A + (size_t)(bm * 256) * K;
    const unsigned short* Bblk = B + (size_t)(bn * 256) * K;

    f32x4 acc[8][4] = {};
    bf16x8 af[4], bfr[4];

    // ---- prologue: stage tile0 fully into buf0, wait kh0 halves ----
    STAGE(0, 0, 0, 0);
    STAGE(1, 0, 0, 0);
    STAGE(0, 1, 0, 0);
    STAGE(1, 1, 0, 0);
    asm volatile("s_waitcnt vmcnt(4)" ::: "memory");
    __builtin_amdgcn_s_barrier();
    __builtin_amdgcn_sched_barrier(0);

    const int NT = K / BK;                   // 64 (even)
    for (int tt = 0; tt < NT; tt += 2) {
        const int kn1 = (tt + 1) * BK;                       // tile tt+1
        const int kn2 = (tt + 2 < NT) ? (tt + 2) * BK : 0;   // wrap: dead stage
        KTILE(0, 1, kn1);
        KTILE(1, 0, kn2);
    }

    // ---- epilogue: bias + store (C/D layout: col=lane&15, row=(lane>>4)*4+r)
    float bv[4];
#pragma unroll
    for (int ni = 0; ni < 4; ++ni)
        bv[ni] = bias[bn * 256 + wc * 64 + ni * 16 + l15];

    const int crow0 = bm * 256 + wr * 128;
    const int ccol = bn * 256 + wc * 64 + l15;
#pragma unroll
    for (int mi = 0; mi < 8; ++mi) {
#pragma unroll
        for (int rr = 0; rr < 4; ++rr) {
            const int row = crow0 + mi * 16 + (lane >> 4) * 4 + rr;
            float* Crow = C + (size_t)row * N;
#pragma unroll
            for (int ni = 0; ni < 4; ++ni)
                Crow[ccol + ni * 16] = acc[mi][ni][rr] + bv[ni];
        }
    }
}

// ---------------------------------------------------------------------------
extern "C" void kernel_launch(void* const* d_in, const int* in_sizes, int n_in,
                              void* d_out, int out_size, void* d_ws, size_t ws_size,
                              hipStream_t stream) {
    const float* x      = (const float*)d_in[0];
    const float* weight = (const float*)d_in[1];
    const float* bias   = (const float*)d_in[2];
    const float* ow     = (const float*)d_in[3];
    const int*   idx    = (const int*)d_in[4];

    const int OC    = in_sizes[2];
    const int n_out = in_sizes[4];
    const int IC    = in_sizes[1] / OC;
    const int M     = in_sizes[0] / IC;
    float* out = (float*)d_out;

    char* ws = (char*)d_ws;
    unsigned short* wq = (unsigned short*)ws;                              // OC*IC bf16
    unsigned short* xb = (unsigned short*)(ws + (size_t)OC * IC * 2);      // M*IC bf16
    int* cm = (int*)(ws + (size_t)OC * IC * 2 + (size_t)M * IC * 2);       // IC ints

    init_colmap_kernel<<<(IC + 255) / 256, 256, 0, stream>>>(cm, IC);
    scatter_colmap_kernel<<<(n_out + 255) / 256, 256, 0, stream>>>(idx, cm, n_out);
    quant_weight_kernel<<<OC, 256, 0, stream>>>(weight, ow, cm, wq, IC, n_out);

    const long n8 = (long)M * IC / 8;
    cast_x_kernel<<<2048, 256, 0, stream>>>((const float4*)x, (us8*)xb, n8);

    hipFuncSetAttribute((const void*)gemm_8phase_kernel,
                        hipFuncAttributeMaxDynamicSharedMemorySize, 131072);
    const int NBM = M / 256, NBN = OC / 256;
    gemm_8phase_kernel<<<dim3(NBM * NBN), dim3(512), 131072, stream>>>(
        xb, wq, bias, out, M, OC, IC, NBN);
}

// Round 3
// 296.977 us; speedup vs baseline: 1.5145x; 1.0468x over previous
//
#include <hip/hip_runtime.h>
#include <hip/hip_bf16.h>

// ---------------------------------------------------------------------------
// OutliersQLinearColumn: out = x @ w^T + bias
// Round 3: 8-phase 256x256 bf16 MFMA GEMM + slot-XOR LDS swizzle (T2).
//   LDS sub-tiles [256 rows][32 k] bf16 (64-B rows, 4x 16-B slots).
//   Swizzle: slot ^= (row>>1)&3, applied on BOTH the staging global source
//   (global_load_lds dest stays linear) and the ds_read slot -> each
//   16-lane ds_read_b128 group covers all 32 banks exactly 2x (floor).
// ---------------------------------------------------------------------------

typedef __attribute__((ext_vector_type(8))) __bf16 bf16x8;
typedef __attribute__((ext_vector_type(4))) float  f32x4;
typedef unsigned short us4 __attribute__((ext_vector_type(4)));
typedef unsigned short us8 __attribute__((ext_vector_type(8)));

__device__ inline unsigned short f2bf(float f) {
    unsigned u = __float_as_uint(f);
    unsigned r = (u + 0x7FFFu + ((u >> 16) & 1u)) >> 16;  // RNE
    return (unsigned short)r;
}

// ---------------------------------------------------------------------------
// col_map: for each input column, outlier slot j landing there (last wins).
// ---------------------------------------------------------------------------
__global__ void init_colmap_kernel(int* __restrict__ cm, int IC) {
    int i = blockIdx.x * 256 + threadIdx.x;
    if (i < IC) cm[i] = -1;
}

__global__ void scatter_colmap_kernel(const int* __restrict__ idx,
                                      int* __restrict__ cm, int n) {
    int j = blockIdx.x * 256 + threadIdx.x;
    if (j < n) atomicMax(&cm[idx[j]], j);
}

// ---------------------------------------------------------------------------
// Quantize one weight row per block (256 threads, IC == 4096).
// ---------------------------------------------------------------------------
__global__ void quant_weight_kernel(const float* __restrict__ w,
                                    const float* __restrict__ ow,
                                    const int* __restrict__ cm,
                                    unsigned short* __restrict__ wq,
                                    int IC, int n_out) {
    __shared__ float red[8];
    const int o = blockIdx.x;
    const int t = threadIdx.x;
    const int lane = t & 63, wid = t >> 6;

    const float4* row4 = (const float4*)(w + (size_t)o * IC);
    float4 v[4];
    float s = 0.f;
#pragma unroll
    for (int j = 0; j < 4; ++j) {
        v[j] = row4[t + j * 256];
        s += v[j].x + v[j].y + v[j].z + v[j].w;
    }
#pragma unroll
    for (int off = 32; off; off >>= 1) s += __shfl_down(s, off);
    if (lane == 0) red[wid] = s;
    __syncthreads();
    const float mean = (red[0] + red[1] + red[2] + red[3]) / (float)IC;

    float a = 0.f;
#pragma unroll
    for (int j = 0; j < 4; ++j)
        a += fabsf(v[j].x - mean) + fabsf(v[j].y - mean) +
             fabsf(v[j].z - mean) + fabsf(v[j].w - mean);
#pragma unroll
    for (int off = 32; off; off >>= 1) a += __shfl_down(a, off);
    if (lane == 0) red[4 + wid] = a;
    __syncthreads();
    const float scale = (red[4] + red[5] + red[6] + red[7]) / (float)IC;

    const size_t base = (size_t)o * IC;
    const float* owr = ow + (size_t)o * n_out;
#pragma unroll
    for (int j = 0; j < 4; ++j) {
        const int c0 = (t + j * 256) * 4;
        float ee[4] = {v[j].x, v[j].y, v[j].z, v[j].w};
        us4 q4;
#pragma unroll
        for (int ei = 0; ei < 4; ++ei) {
            float c = ee[ei] - mean;
            float q = c > 0.f ? scale : (c < 0.f ? -scale : 0.f);
            int m = cm[c0 + ei];
            if (m >= 0) q = owr[m];
            q4[ei] = f2bf(q);
        }
        *(us4*)&wq[base + c0] = q4;
    }
}

// ---------------------------------------------------------------------------
// Cast x f32 -> bf16, 8 elements/thread/iter, grid-stride.
// ---------------------------------------------------------------------------
__global__ void cast_x_kernel(const float4* __restrict__ x4,
                              us8* __restrict__ xb, long n8) {
    long i = (long)blockIdx.x * blockDim.x + threadIdx.x;
    const long stride = (long)gridDim.x * blockDim.x;
    for (; i < n8; i += stride) {
        float4 a = x4[i * 2], b = x4[i * 2 + 1];
        us8 o;
        o[0] = f2bf(a.x); o[1] = f2bf(a.y); o[2] = f2bf(a.z); o[3] = f2bf(a.w);
        o[4] = f2bf(b.x); o[5] = f2bf(b.y); o[6] = f2bf(b.z); o[7] = f2bf(b.w);
        xb[i] = o;
    }
}

// ---------------------------------------------------------------------------
// 8-phase 256x256 GEMM: C[M,N] = A[M,K](bf16) * B[N,K](bf16)^T + bias.
// 512 threads = 8 waves (2 M x 4 N), per-wave output 128x64.
// LDS (dynamic 128 KiB): lds[buf2][mat2][kh2][256 rows][32 k] bf16.
// Slot swizzle: physical_slot = logical_slot ^ ((row>>1)&3).
//   read slot  -> (lane>>4) ^ ((lane>>1)&3)      (row = ... + (lane&15))
//   stage gsrc -> (lane&3)  ^ ((lane>>3)&3)      (row = ... + (lane>>2))
// ---------------------------------------------------------------------------
#define BK 64

#define GLDS(src, dst) __builtin_amdgcn_global_load_lds( \
    (const __attribute__((address_space(1))) void*)(src), \
    (__attribute__((address_space(3))) void*)(dst), 16, 0, 0)

// Stage half-tile (MAT: 0=A,1=B ; KHS: k-half) of the tile at k-offset kn
// into buffer bufS. 2 x global_load_lds per thread (512 thr x 16 B x 2 = 16 KB).
#define STAGE(MAT, KHS, bufS, kn) do {                                        \
    const unsigned short* gsrc_ = (MAT) ? Bblk : Ablk;                        \
    _Pragma("unroll")                                                         \
    for (int rr_ = 0; rr_ < 2; ++rr_) {                                       \
      GLDS(gsrc_ + (size_t)(rr_ * 128 + stg_row) * K + (kn) + (KHS) * 32 + stg_col, \
           &lds[(bufS) * 32768 + (MAT) * 16384 + (KHS) * 8192 +               \
                (rr_ * 128 + wid * 16) * 32]);                                \
    } } while (0)

#define PHASE(FH, KH, DOBF, STMAT, STKH, VM, bufR, bufS, kn) do {             \
    const unsigned short* pA_ = &lds[(bufR) * 32768 + (KH) * 8192];           \
    const unsigned short* pB_ = &lds[(bufR) * 32768 + 16384 + (KH) * 8192];   \
    _Pragma("unroll")                                                         \
    for (int j_ = 0; j_ < 4; ++j_)                                            \
      af[j_] = *(const bf16x8*)&pA_[(wr * 128 + ((FH) * 4 + j_) * 16 + l15) * 32 + sl8]; \
    if (DOBF) {                                                               \
      _Pragma("unroll")                                                       \
      for (int j_ = 0; j_ < 4; ++j_)                                          \
        bfr[j_] = *(const bf16x8*)&pB_[(wc * 64 + j_ * 16 + l15) * 32 + sl8]; \
    }                                                                         \
    STAGE(STMAT, STKH, bufS, kn);                                             \
    if (VM) asm volatile("s_waitcnt vmcnt(4)" ::: "memory");                  \
    __builtin_amdgcn_s_barrier();                                             \
    asm volatile("s_waitcnt lgkmcnt(0)" ::: "memory");                        \
    __builtin_amdgcn_sched_barrier(0);                                        \
    __builtin_amdgcn_s_setprio(1);                                            \
    _Pragma("unroll")                                                         \
    for (int mi_ = 0; mi_ < 4; ++mi_)                                         \
      _Pragma("unroll")                                                       \
      for (int ni_ = 0; ni_ < 4; ++ni_)                                       \
        acc[(FH) * 4 + mi_][ni_] = __builtin_amdgcn_mfma_f32_16x16x32_bf16(   \
            af[mi_], bfr[ni_], acc[(FH) * 4 + mi_][ni_], 0, 0, 0);            \
    __builtin_amdgcn_s_setprio(0);                                            \
    __builtin_amdgcn_s_barrier();                                             \
  } while (0)

// One K-tile = 4 phases. Stages the NEXT tile (k-offset kn) into bufS.
// vmcnt(4) at end of P1 (drains prev P2/P3 = this tile's kh1) and P3
// (drains this P0/P1 = next tile's kh0). Never 0 in the main loop.
#define KTILE(bufR, bufS, kn) do {                                            \
    PHASE(0, 0, true,  0, 0, false, bufR, bufS, kn);                          \
    PHASE(1, 0, false, 1, 0, true,  bufR, bufS, kn);                          \
    PHASE(0, 1, true,  0, 1, false, bufR, bufS, kn);                          \
    PHASE(1, 1, false, 1, 1, true,  bufR, bufS, kn);                          \
  } while (0)

__global__ __launch_bounds__(512, 2) void gemm_8phase_kernel(
    const unsigned short* __restrict__ A,   // [M,K] bf16 bits
    const unsigned short* __restrict__ B,   // [N,K] bf16 bits
    const float* __restrict__ bias,         // [N]
    float* __restrict__ C,                  // [M,N] f32
    int M, int N, int K, int NBN) {
    extern __shared__ unsigned short lds[];  // 131072 B

    const int t = threadIdx.x;
    const int wid = t >> 6, lane = t & 63;
    const int l15 = lane & 15;
    // read-side swizzled slot (elements): ((lane>>4) ^ ((row>>1)&3)) * 8,
    // row prefix terms are multiples of 16 so (row>>1)&3 == ((lane&15)>>1)&3
    const int sl8 = (((lane >> 4) ^ ((lane >> 1) & 3)) & 3) * 8;
    const int wr = wid >> 2;                 // 0..1  (M half)
    const int wc = wid & 3;                  // 0..3  (N quarter)
    const int stg_row = wid * 16 + (lane >> 2);
    // stage-side swizzled global source slot (elements)
    const int stg_col = (((lane & 3) ^ ((lane >> 3) & 3)) & 3) * 8;

    // bijective XCD swizzle (m204)
    const int nwg = gridDim.x;
    const int bid = blockIdx.x;
    const int q = nwg >> 3, r = nwg & 7;
    const int xcd = bid & 7, off = bid >> 3;
    const int swz = (xcd < r ? xcd * (q + 1) : r * (q + 1) + (xcd - r) * q) + off;
    const int bm = swz / NBN, bn = swz % NBN;

    const unsigned short* Ablk = A + (size_t)(bm * 256) * K;
    const unsigned short* Bblk = B + (size_t)(bn * 256) * K;

    f32x4 acc[8][4] = {};
    bf16x8 af[4], bfr[4];

    // ---- prologue: stage tile0 fully into buf0, wait kh0 halves ----
    STAGE(0, 0, 0, 0);
    STAGE(1, 0, 0, 0);
    STAGE(0, 1, 0, 0);
    STAGE(1, 1, 0, 0);
    asm volatile("s_waitcnt vmcnt(4)" ::: "memory");
    __builtin_amdgcn_s_barrier();
    __builtin_amdgcn_sched_barrier(0);

    const int NT = K / BK;                   // 64 (even)
    for (int tt = 0; tt < NT; tt += 2) {
        const int kn1 = (tt + 1) * BK;                       // tile tt+1
        const int kn2 = (tt + 2 < NT) ? (tt + 2) * BK : 0;   // wrap: dead stage
        KTILE(0, 1, kn1);
        KTILE(1, 0, kn2);
    }

    // ---- epilogue: bias + store (C/D layout: col=lane&15, row=(lane>>4)*4+r)
    float bv[4];
#pragma unroll
    for (int ni = 0; ni < 4; ++ni)
        bv[ni] = bias[bn * 256 + wc * 64 + ni * 16 + l15];

    const int crow0 = bm * 256 + wr * 128;
    const int ccol = bn * 256 + wc * 64 + l15;
#pragma unroll
    for (int mi = 0; mi < 8; ++mi) {
#pragma unroll
        for (int rr = 0; rr < 4; ++rr) {
            const int row = crow0 + mi * 16 + (lane >> 4) * 4 + rr;
            float* Crow = C + (size_t)row * N;
#pragma unroll
            for (int ni = 0; ni < 4; ++ni)
                Crow[ccol + ni * 16] = acc[mi][ni][rr] + bv[ni];
        }
    }
}

// ---------------------------------------------------------------------------
extern "C" void kernel_launch(void* const* d_in, const int* in_sizes, int n_in,
                              void* d_out, int out_size, void* d_ws, size_t ws_size,
                              hipStream_t stream) {
    const float* x      = (const float*)d_in[0];
    const float* weight = (const float*)d_in[1];
    const float* bias   = (const float*)d_in[2];
    const float* ow     = (const float*)d_in[3];
    const int*   idx    = (const int*)d_in[4];

    const int OC    = in_sizes[2];
    const int n_out = in_sizes[4];
    const int IC    = in_sizes[1] / OC;
    const int M     = in_sizes[0] / IC;
    float* out = (float*)d_out;

    char* ws = (char*)d_ws;
    unsigned short* wq = (unsigned short*)ws;                              // OC*IC bf16
    unsigned short* xb = (unsigned short*)(ws + (size_t)OC * IC * 2);      // M*IC bf16
    int* cm = (int*)(ws + (size_t)OC * IC * 2 + (size_t)M * IC * 2);       // IC ints

    init_colmap_kernel<<<(IC + 255) / 256, 256, 0, stream>>>(cm, IC);
    scatter_colmap_kernel<<<(n_out + 255) / 256, 256, 0, stream>>>(idx, cm, n_out);
    quant_weight_kernel<<<OC, 256, 0, stream>>>(weight, ow, cm, wq, IC, n_out);

    const long n8 = (long)M * IC / 8;
    cast_x_kernel<<<2048, 256, 0, stream>>>((const float4*)x, (us8*)xb, n8);

    hipFuncSetAttribute((const void*)gemm_8phase_kernel,
                        hipFuncAttributeMaxDynamicSharedMemorySize, 131072);
    const int NBM = M / 256, NBN = OC / 256;
    gemm_8phase_kernel<<<dim3(NBM * NBN), dim3(512), 131072, stream>>>(
        xb, wq, bias, out, M, OC, IC, NBN);
}